// Round 4
// baseline (137.632 us; speedup 1.0000x reference)
//
#include <hip/hip_runtime.h>
#include <hip/hip_bf16.h>

typedef __bf16 bf16x8 __attribute__((ext_vector_type(8)));
typedef float floatx4 __attribute__((ext_vector_type(4)));
typedef unsigned short u16;
typedef unsigned int u32;

#define HW 196      // 14*14
#define NB 8
#define NC 128
#define CL 480      // xfe row stride (u16)
#define WROW 12544  // u32 per (b,a1) row of W (= 25088 bf16 = 128c * 196p)

// ws offsets (bytes)
#define OFF_XFRSW 0            // 8 * 3584 uint4 = 458752 B  (A in MFMA-frag order)
#define OFF_XFE   458752       // 8*128*8*480*2 = 7864320 B  (8 shift-copies / row)
#define OFF_W     8323072      // 12845056 B
#define OFF_Y     21168160     // 8*128*256*4 = 1048576 B   (post-ReLU conv out, fp32)
#define OFF_XBT   22216736     // 8*256*512*2 = 2097152 B   (x^T bf16: [b][pix][k])
#define OFF_WB    24313888     // 128*512*2   = 131072 B    (w bf16: [o][k])
#define OFF_PARTS 24444960     // 256*4 = 1024 B            (per-block sum partials)
#define OFF_DONE  24445984     // 8*4 = 32 B                (per-batch done counters)

// ---- Stage 0: cast x (transposed) and w to bf16; zero done[] counters ----
// blocks 0..511: x-part; 512..543: w-part. 256 thr.
__global__ __launch_bounds__(256) void k_cast(const float* __restrict__ x,
                                              const float* __restrict__ wc,
                                              u16* __restrict__ xbT,
                                              u16* __restrict__ wb,
                                              u32* __restrict__ done) {
  const int bid = blockIdx.x;
  const int t   = threadIdx.x;
  if (bid < 512) {
    const int gid = bid * 256 + t;
    const int pix = gid & 255;          // lanes -> consecutive pix: coalesced reads
    const int kc  = (gid >> 8) & 63;    // 8-k chunk
    const int b   = gid >> 14;
    union { u16 u[8]; uint4 v; } pk;
#pragma unroll
    for (int j = 0; j < 8; ++j) {
      union { __hip_bfloat16 h; u16 u; } cv;
      cv.h = __float2bfloat16(x[((size_t)(b * 512 + kc * 8 + j)) * 256 + pix]);
      pk.u[j] = cv.u;
    }
    ((uint4*)xbT)[(size_t)(b * 256 + pix) * 64 + kc] = pk.v;
  } else {
    if (bid == 543 && t < 8) atomicExch(&done[t], 0u);   // re-zero each iteration
    const int wid = (bid - 512) * 256 + t;   // 0..8191, 8 elems each
    const float4* wf4 = (const float4*)wc;
    const float4 f0 = wf4[wid * 2], f1 = wf4[wid * 2 + 1];
    union { u16 u[8]; uint4 v; } pk;
    union { __hip_bfloat16 h; u16 u; } cv;
    cv.h = __float2bfloat16(f0.x); pk.u[0] = cv.u;
    cv.h = __float2bfloat16(f0.y); pk.u[1] = cv.u;
    cv.h = __float2bfloat16(f0.z); pk.u[2] = cv.u;
    cv.h = __float2bfloat16(f0.w); pk.u[3] = cv.u;
    cv.h = __float2bfloat16(f1.x); pk.u[4] = cv.u;
    cv.h = __float2bfloat16(f1.y); pk.u[5] = cv.u;
    cv.h = __float2bfloat16(f1.z); pk.u[6] = cv.u;
    cv.h = __float2bfloat16(f1.w); pk.u[7] = cv.u;
    ((uint4*)wb)[wid] = pk.v;
  }
}

// ---- Stage 1: 1x1-conv GEMM via MFMA 16x16x32 bf16 + ReLU -> Y[b][o][pix] fp32 ----
// (exact R0 form — R3's fusion into k_blur regressed: 64-block grid choked the
// xfe store bandwidth. Keep the 128/256-block split.)
__global__ __launch_bounds__(256) void k_conv(const u16* __restrict__ xbT,
                                              const u16* __restrict__ wb,
                                              float* __restrict__ Y) {
  const int b  = blockIdx.x;
  const int pt = blockIdx.y;
  const int t  = threadIdx.x;
  const int lane = t & 63, wv = t >> 6;
  const int n = lane & 15, quad = lane >> 4;
  const int pix = pt * 16 + n;

  const u16* xrow = xbT + ((size_t)(b * 256) + pix) * 512 + quad * 8;
  const u16* wrow = wb + (size_t)n * 512 + quad * 8;

  floatx4 acc[2];
  acc[0] = (floatx4){0.f, 0.f, 0.f, 0.f};
  acc[1] = (floatx4){0.f, 0.f, 0.f, 0.f};

#pragma unroll
  for (int kb = 0; kb < 16; ++kb) {
    const bf16x8 bv = *(const bf16x8*)(xrow + kb * 32);
#pragma unroll
    for (int j = 0; j < 2; ++j) {
      const int at = wv * 2 + j;
      const bf16x8 av = *(const bf16x8*)(wrow + (size_t)(at * 16) * 512 + kb * 32);
      acc[j] = __builtin_amdgcn_mfma_f32_16x16x32_bf16(av, bv, acc[j], 0, 0, 0);
    }
  }

  float* Yb = Y + ((size_t)b * 128) * 256 + pix;
#pragma unroll
  for (int j = 0; j < 2; ++j)
#pragma unroll
    for (int rr = 0; rr < 4; ++rr)
      Yb[((wv * 2 + j) * 16 + quad * 4 + rr) * 256] = fmaxf(acc[j][rr], 0.f);
}

// ---- Stage 1b: 3x3 Gaussian blur + bf16 + operand repack (exact R0 form) ----
__global__ __launch_bounds__(256) void k_blur(const float* __restrict__ Y,
                                              uint4* __restrict__ xfr_sw,
                                              u16* __restrict__ xfe) {
  const int b  = blockIdx.x;
  const int rg = blockIdx.y;       // rows rg*4 .. +3
  const int t  = threadIdx.x;      // pixel

  __shared__ float ybuf[4][256];
  __shared__ u16 ydup[4][592];     // blurred row bf16, replicated 3x (idx 0..587)

#pragma unroll
  for (int oo = 0; oo < 4; ++oo)
    ybuf[oo][t] = Y[((size_t)(b * 128) + rg * 4 + oo) * 256 + t];  // already ReLU'd
  __syncthreads();

  const float GC = 0.63661977236758138f;   // gaussian var 0.25
  const float GE = GC * 0.13533528323661270f;
  const float GD = GC * 0.018315638888734179f;

  if (t < HW) {
    const int h = t / 14, w2 = t - h * 14;
#pragma unroll
    for (int oo = 0; oo < 4; ++oo) {
      const float* yb = &ybuf[oo][h * 16 + w2];
      float v = GD * (yb[0] + yb[2] + yb[32] + yb[34])
              + GE * (yb[1] + yb[16] + yb[18] + yb[33])
              + GC * yb[17];
      union { __hip_bfloat16 h2; u16 u; } cv; cv.h2 = __float2bfloat16(v);
      ydup[oo][t] = cv.u; ydup[oo][t + 196] = cv.u; ydup[oo][t + 392] = cv.u;
    }
  }
  __syncthreads();

  // xfr_sw: per row 28 uint4 (g = kb*4+quad), Arev[k] = y[(196-k)%196], 0 for k>=196
  if (t < 112) {
    const int oo = t / 28;
    const int g  = t - oo * 28;
    const int kb = g >> 2, quad = g & 3;
    const int c  = rg * 4 + oo;
    const int at = c >> 4, m = c & 15;
    union { u16 u[8]; uint4 v; } pk;
#pragma unroll
    for (int j = 0; j < 8; ++j) {
      const int k = g * 8 + j;
      pk.u[j] = (k < HW) ? ydup[oo][HW - k] : (u16)0;
    }
    xfr_sw[b * 3584 + ((kb * 8 + at) * 4 + quad) * 16 + m] = pk.v;
  }

  // xfe: 4 rows x 8 shifts x 60 uint4
  uint4* xfe4 = (uint4*)xfe;
  for (int idx = t; idx < 4 * 8 * 60; idx += 256) {
    const int oo = idx / 480;
    const int rem = idx - oo * 480;
    const int S = rem / 60;
    const int g = rem - S * 60;
    const int c = rg * 4 + oo;
    union { u16 u[8]; uint4 v; } pk;
#pragma unroll
    for (int j = 0; j < 8; ++j) pk.u[j] = ydup[oo][g * 8 + j + S];  // <= 487 < 588
    xfe4[((size_t)(b * NC + c) * 8 + S) * 60 + g] = pk.v;
  }
}

// ---- Stage 2: circular correlation via MFMA (exact R0 form; setprio null-to-
// negative here per R2 A/B — identical barrier-free waves, nothing to arbitrate) ----
__global__ __launch_bounds__(256, 2) void k_cooc(const uint4* __restrict__ xfr_sw,
                                                 const u16* __restrict__ xfe,
                                                 u32* __restrict__ W) {
  const int b     = blockIdx.x;
  const int cpair = blockIdx.y;
  const int t     = threadIdx.x;

  __shared__ __align__(16) uint4 Abuf[3584];   // 57344 B, frag order
  __shared__ __align__(16) u16 Obuf[32 * 200]; // 12800 B

  { // flat coalesced staging (xfr_sw is XCD-L2 resident)
    const uint4* src = xfr_sw + b * 3584;
    for (int j = t; j < 3584; j += 256) Abuf[j] = src[j];
  }
  __syncthreads();

  const int lane = t & 63;
  const int wv   = t >> 6;       // p-tiles {wv, wv+4, wv+8} (+12 for wave 0)
  const int n    = lane & 15;
  const int quad = lane >> 4;
  const u16* xbase = xfe + ((size_t)(b * NC) * 8) * CL + (n & 8) + quad * 8
                   + (size_t)(n & 7) * CL;

  for (int c2 = 0; c2 < 2; ++c2) {
    const int c = cpair * 2 + c2;
    const u16* xc = xbase + (size_t)c * (8 * CL);

    floatx4 acc[8][4];
#pragma unroll
    for (int at = 0; at < 8; ++at)
#pragma unroll
      for (int j = 0; j < 4; ++j) acc[at][j] = (floatx4){0.f, 0.f, 0.f, 0.f};

    for (int kb = 0; kb < 7; ++kb) {
      bf16x8 af[8];
#pragma unroll
      for (int at = 0; at < 8; ++at)   // lane-contiguous: base + lane*16B, no conflicts
        af[at] = *((const bf16x8*)&Abuf[(kb * 8 + at) * 64 + lane]);

#define DO_PT(JC)                                                                \
      {                                                                          \
        const int p0 = (wv + 4 * (JC)) * 16;                                     \
        const bf16x8 bv = *((const bf16x8*)&xc[p0 + kb * 32]);                   \
        _Pragma("unroll")                                                        \
        for (int at = 0; at < 8; ++at)                                           \
          acc[at][JC] = __builtin_amdgcn_mfma_f32_16x16x32_bf16(af[at], bv,      \
                                                                acc[at][JC], 0, 0, 0); \
      }
      DO_PT(0)
      DO_PT(1)
      DO_PT(2)
      if (wv == 0) { DO_PT(3) }
#undef DO_PT
    }

#define EPI(JC)                                                                  \
    {                                                                            \
      const int p = (wv + 4 * (JC)) * 16 + n;                                    \
      if (p < HW) {                                                              \
        _Pragma("unroll")                                                        \
        for (int a0t = 0; a0t < 2; ++a0t) {                                      \
          _Pragma("unroll")                                                      \
          for (int rr = 0; rr < 4; ++rr) {                                       \
            float v = fmaxf(fmaxf(acc[a0t][JC][rr], acc[a0t + 2][JC][rr]),       \
                            fmaxf(acc[a0t + 4][JC][rr], acc[a0t + 6][JC][rr]));  \
            const int a1 = a0t * 16 + quad * 4 + rr;                             \
            union { __hip_bfloat16 h; u16 u; } cv;                               \
            cv.h = __float2bfloat16(v);                                          \
            Obuf[a1 * 200 + p] = cv.u;                                           \
          }                                                                      \
        }                                                                        \
      }                                                                          \
    }
    EPI(0)
    EPI(1)
    EPI(2)
    if (wv == 0) { EPI(3) }
#undef EPI
    __syncthreads();

    { // coalesced store: 32 rows x 98 u32 into W[b][a1][c*98 + col]
      const u32* O32 = (const u32*)Obuf;
      u32* Wb = W + ((size_t)b * 32) * WROW + c * 98;
      for (int j = t; j < 32 * 98; j += 256) {
        const int row = (int)(((unsigned)j * 10700u) >> 20);   // j / 98
        const int col = j - row * 98;
        Wb[row * WROW + col] = O32[row * 100 + col];
      }
    }
    __syncthreads();
  }
}

__device__ __forceinline__ float blo(u32 v) { return __uint_as_float(v << 16); }
__device__ __forceinline__ float bhi(u32 v) { return __uint_as_float(v & 0xffff0000u); }

// ---- Stage 3+4 fused (R14): per-slot max + device-atomic spin barrier + norm ----
// Phase 1 = exact old k_max (same maxes, same parts values, same sqrt). Then:
// parts stored with agent-scope atomics, done[b] incremented, t==0 spins until
// all 32 blocks of its batch posted (all 256 blocks trivially co-resident:
// capacity ~2048 block-slots; bounded spin as a hang guard). Sum read back in
// the SAME i=0..31 order as old k_norm -> bit-identical result. No cooperative
// launch (R1's hang), no plain cross-XCD reads (G16: atomics both sides).
__global__ __launch_bounds__(256) void k_maxnorm(const u32* __restrict__ W,
                                                 float* __restrict__ out,
                                                 float* __restrict__ parts,
                                                 u32* __restrict__ done) {
  const int t = threadIdx.x;
  const int wv = t >> 6, lane = t & 63;
  const int g = lane >> 4, ol = lane & 15;
  const int octet = blockIdx.x * 64 + wv * 16 + ol;   // 0..16383
  const int b  = octet >> 11;                          // uniform per block (64|2048)
  const int r0 = (octet & 2047) << 3;
  const uint4* Wb = (const uint4*)(W + (size_t)b * 32 * WROW);

  float m[8];
#pragma unroll
  for (int j = 0; j < 8; ++j) m[j] = 0.f;

#pragma unroll
  for (int k = 0; k < 8; ++k) {
    const int a1 = g * 8 + k;
    const int s = (r0 - ((a1 * 8704) & 16383)) & 16383;   // 8-aligned
    const uint4 v = Wb[(a1 * WROW + (s >> 1)) >> 2];
    m[0] = fmaxf(m[0], blo(v.x)); m[1] = fmaxf(m[1], bhi(v.x));
    m[2] = fmaxf(m[2], blo(v.y)); m[3] = fmaxf(m[3], bhi(v.y));
    m[4] = fmaxf(m[4], blo(v.z)); m[5] = fmaxf(m[5], bhi(v.z));
    m[6] = fmaxf(m[6], blo(v.w)); m[7] = fmaxf(m[7], bhi(v.w));
    if (s < 8704) {   // second contributor s+16384 < 25088
      const uint4 v2 = Wb[((a1 * WROW + (s >> 1)) >> 2) + 2048];
      m[0] = fmaxf(m[0], blo(v2.x)); m[1] = fmaxf(m[1], bhi(v2.x));
      m[2] = fmaxf(m[2], blo(v2.y)); m[3] = fmaxf(m[3], bhi(v2.y));
      m[4] = fmaxf(m[4], blo(v2.z)); m[5] = fmaxf(m[5], bhi(v2.z));
      m[6] = fmaxf(m[6], blo(v2.w)); m[7] = fmaxf(m[7], bhi(v2.w));
    }
  }

  // combine the 4 a1-groups (lanes stride 16)
#pragma unroll
  for (int j = 0; j < 8; ++j) {
    m[j] = fmaxf(m[j], __shfl_xor(m[j], 16, 64));
    m[j] = fmaxf(m[j], __shfl_xor(m[j], 32, 64));
  }

  float s2 = 0.f;
  float4 s0 = {0.f, 0.f, 0.f, 0.f}, s1 = {0.f, 0.f, 0.f, 0.f};
  if (g == 0) {
    s0.x = sqrtf(m[0]); s0.y = sqrtf(m[1]); s0.z = sqrtf(m[2]); s0.w = sqrtf(m[3]);
    s1.x = sqrtf(m[4]); s1.y = sqrtf(m[5]); s1.z = sqrtf(m[6]); s1.w = sqrtf(m[7]);
    s2 = ((m[0] + m[1]) + (m[2] + m[3])) + ((m[4] + m[5]) + (m[6] + m[7]));
  }

  // per-batch sum of c_ij^2: wave reduce (non-g0 lanes carry 0) then block
#pragma unroll
  for (int off = 32; off > 0; off >>= 1) s2 += __shfl_down(s2, off, 64);
  __shared__ float part[4];
  if (lane == 0) part[wv] = s2;
  __syncthreads();

  if (t == 0) {
    const float psum = part[0] + part[1] + part[2] + part[3];
    __hip_atomic_store(&parts[blockIdx.x], psum, __ATOMIC_RELAXED,
                       __HIP_MEMORY_SCOPE_AGENT);
    __threadfence();                      // release parts before done++
    atomicAdd(&done[b], 1u);              // device scope
    u32 iters = 0;
    while (__hip_atomic_load(&done[b], __ATOMIC_RELAXED,
                             __HIP_MEMORY_SCOPE_AGENT) < 32u) {
      __builtin_amdgcn_s_sleep(8);        // backoff
      if (++iters > (1u << 26)) break;    // hang guard (never hit: co-resident)
    }
  }
  __syncthreads();
  __threadfence();                        // acquire

  __shared__ float ps[32];
  if (t < 32)
    ps[t] = __hip_atomic_load(&parts[b * 32 + t], __ATOMIC_RELAXED,
                              __HIP_MEMORY_SCOPE_AGENT);
  __syncthreads();
  float ssum = 0.f;
#pragma unroll
  for (int i = 0; i < 32; ++i) ssum += ps[i];   // same order as old k_norm
  const float den = ssum + 1e-11f;

  if (g == 0) {
    float4 o0, o1;
    o0.x = s0.x / den; o0.y = s0.y / den; o0.z = s0.z / den; o0.w = s0.w / den;
    o1.x = s1.x / den; o1.y = s1.y / den; o1.z = s1.z / den; o1.w = s1.w / den;
    float4* op = (float4*)(out + (size_t)octet * 8);
    op[0] = o0; op[1] = o1;
  }
}

extern "C" void kernel_launch(void* const* d_in, const int* in_sizes, int n_in,
                              void* d_out, int out_size, void* d_ws, size_t ws_size,
                              hipStream_t stream) {
  const float* x  = (const float*)d_in[0];   // (8,512,16,16) fp32
  const float* wc = (const float*)d_in[1];   // (128,512) fp32

  char* ws = (char*)d_ws;
  uint4* xfr_sw = (uint4*)(ws + OFF_XFRSW);
  u16*   xfe    = (u16*)(ws + OFF_XFE);
  u32*   W      = (u32*)(ws + OFF_W);
  float* Y      = (float*)(ws + OFF_Y);
  u16*   xbT    = (u16*)(ws + OFF_XBT);
  u16*   wb     = (u16*)(ws + OFF_WB);
  float* parts  = (float*)(ws + OFF_PARTS);
  u32*   done   = (u32*)(ws + OFF_DONE);

  k_cast<<<544, 256, 0, stream>>>(x, wc, xbT, wb, done);
  k_conv<<<dim3(NB, 16), 256, 0, stream>>>(xbT, wb, Y);
  k_blur<<<dim3(NB, 32), 256, 0, stream>>>(Y, xfr_sw, xfe);
  k_cooc<<<dim3(NB, 64), 256, 0, stream>>>(xfr_sw, xfe, W);
  k_maxnorm<<<256, 256, 0, stream>>>(W, (float*)d_out, parts, done);
}

// Round 5
// 109.273 us; speedup vs baseline: 1.2595x; 1.2595x over previous
//
#include <hip/hip_runtime.h>
#include <hip/hip_bf16.h>

typedef __bf16 bf16x8 __attribute__((ext_vector_type(8)));
typedef float floatx4 __attribute__((ext_vector_type(4)));
typedef unsigned short u16;
typedef unsigned int u32;

#define HW 196      // 14*14
#define NB 8
#define NC 128
#define CL 480      // xfe row stride (u16)
#define WROW 12544  // u32 per (b,a1) row of W (= 25088 bf16 = 128c * 196p)

// ws offsets (bytes)
#define OFF_XFRSW 0            // 8 * 3584 uint4 = 458752 B  (A in MFMA-frag order)
#define OFF_XFE   458752       // 8*128*8*480*2 = 7864320 B  (8 shift-copies / row)
#define OFF_W     8323072      // 12845056 B
#define OFF_Y     21168160     // 8*128*256*4 = 1048576 B   (post-ReLU conv out, fp32)
#define OFF_XBT   22216736     // 8*256*512*2 = 2097152 B   (x^T bf16: [b][pix][k])
#define OFF_WB    24313888     // 128*512*2   = 131072 B    (w bf16: [o][k])
#define OFF_PARTS 24444960     // 256*4 = 1024 B            (per-block sum partials)

// ---- Stage 0: cast x (transposed) and w to bf16 ----
// blocks 0..511: x-part; 512..543: w-part. 256 thr. (exact R0 form)
__global__ __launch_bounds__(256) void k_cast(const float* __restrict__ x,
                                              const float* __restrict__ wc,
                                              u16* __restrict__ xbT,
                                              u16* __restrict__ wb) {
  const int bid = blockIdx.x;
  const int t   = threadIdx.x;
  if (bid < 512) {
    const int gid = bid * 256 + t;
    const int pix = gid & 255;          // lanes -> consecutive pix: coalesced reads
    const int kc  = (gid >> 8) & 63;    // 8-k chunk
    const int b   = gid >> 14;
    union { u16 u[8]; uint4 v; } pk;
#pragma unroll
    for (int j = 0; j < 8; ++j) {
      union { __hip_bfloat16 h; u16 u; } cv;
      cv.h = __float2bfloat16(x[((size_t)(b * 512 + kc * 8 + j)) * 256 + pix]);
      pk.u[j] = cv.u;
    }
    ((uint4*)xbT)[(size_t)(b * 256 + pix) * 64 + kc] = pk.v;
  } else {
    const int wid = (bid - 512) * 256 + t;   // 0..8191, 8 elems each
    const float4* wf4 = (const float4*)wc;
    const float4 f0 = wf4[wid * 2], f1 = wf4[wid * 2 + 1];
    union { u16 u[8]; uint4 v; } pk;
    union { __hip_bfloat16 h; u16 u; } cv;
    cv.h = __float2bfloat16(f0.x); pk.u[0] = cv.u;
    cv.h = __float2bfloat16(f0.y); pk.u[1] = cv.u;
    cv.h = __float2bfloat16(f0.z); pk.u[2] = cv.u;
    cv.h = __float2bfloat16(f0.w); pk.u[3] = cv.u;
    cv.h = __float2bfloat16(f1.x); pk.u[4] = cv.u;
    cv.h = __float2bfloat16(f1.y); pk.u[5] = cv.u;
    cv.h = __float2bfloat16(f1.z); pk.u[6] = cv.u;
    cv.h = __float2bfloat16(f1.w); pk.u[7] = cv.u;
    ((uint4*)wb)[wid] = pk.v;
  }
}

// ---- Stage 1: 1x1-conv GEMM via MFMA 16x16x32 bf16 + ReLU -> Y[b][o][pix] fp32 ----
// (exact R0 form)
__global__ __launch_bounds__(256) void k_conv(const u16* __restrict__ xbT,
                                              const u16* __restrict__ wb,
                                              float* __restrict__ Y) {
  const int b  = blockIdx.x;
  const int pt = blockIdx.y;
  const int t  = threadIdx.x;
  const int lane = t & 63, wv = t >> 6;
  const int n = lane & 15, quad = lane >> 4;
  const int pix = pt * 16 + n;

  const u16* xrow = xbT + ((size_t)(b * 256) + pix) * 512 + quad * 8;
  const u16* wrow = wb + (size_t)n * 512 + quad * 8;

  floatx4 acc[2];
  acc[0] = (floatx4){0.f, 0.f, 0.f, 0.f};
  acc[1] = (floatx4){0.f, 0.f, 0.f, 0.f};

#pragma unroll
  for (int kb = 0; kb < 16; ++kb) {
    const bf16x8 bv = *(const bf16x8*)(xrow + kb * 32);
#pragma unroll
    for (int j = 0; j < 2; ++j) {
      const int at = wv * 2 + j;
      const bf16x8 av = *(const bf16x8*)(wrow + (size_t)(at * 16) * 512 + kb * 32);
      acc[j] = __builtin_amdgcn_mfma_f32_16x16x32_bf16(av, bv, acc[j], 0, 0, 0);
    }
  }

  float* Yb = Y + ((size_t)b * 128) * 256 + pix;
#pragma unroll
  for (int j = 0; j < 2; ++j)
#pragma unroll
    for (int rr = 0; rr < 4; ++rr)
      Yb[((wv * 2 + j) * 16 + quad * 4 + rr) * 256] = fmaxf(acc[j][rr], 0.f);
}

// ---- Stage 1b: 3x3 Gaussian blur + bf16 + operand repack (exact R0 form) ----
__global__ __launch_bounds__(256) void k_blur(const float* __restrict__ Y,
                                              uint4* __restrict__ xfr_sw,
                                              u16* __restrict__ xfe) {
  const int b  = blockIdx.x;
  const int rg = blockIdx.y;       // rows rg*4 .. +3
  const int t  = threadIdx.x;      // pixel

  __shared__ float ybuf[4][256];
  __shared__ u16 ydup[4][592];     // blurred row bf16, replicated 3x (idx 0..587)

#pragma unroll
  for (int oo = 0; oo < 4; ++oo)
    ybuf[oo][t] = Y[((size_t)(b * 128) + rg * 4 + oo) * 256 + t];  // already ReLU'd
  __syncthreads();

  const float GC = 0.63661977236758138f;   // gaussian var 0.25
  const float GE = GC * 0.13533528323661270f;
  const float GD = GC * 0.018315638888734179f;

  if (t < HW) {
    const int h = t / 14, w2 = t - h * 14;
#pragma unroll
    for (int oo = 0; oo < 4; ++oo) {
      const float* yb = &ybuf[oo][h * 16 + w2];
      float v = GD * (yb[0] + yb[2] + yb[32] + yb[34])
              + GE * (yb[1] + yb[16] + yb[18] + yb[33])
              + GC * yb[17];
      union { __hip_bfloat16 h2; u16 u; } cv; cv.h2 = __float2bfloat16(v);
      ydup[oo][t] = cv.u; ydup[oo][t + 196] = cv.u; ydup[oo][t + 392] = cv.u;
    }
  }
  __syncthreads();

  // xfr_sw: per row 28 uint4 (g = kb*4+quad), Arev[k] = y[(196-k)%196], 0 for k>=196
  if (t < 112) {
    const int oo = t / 28;
    const int g  = t - oo * 28;
    const int kb = g >> 2, quad = g & 3;
    const int c  = rg * 4 + oo;
    const int at = c >> 4, m = c & 15;
    union { u16 u[8]; uint4 v; } pk;
#pragma unroll
    for (int j = 0; j < 8; ++j) {
      const int k = g * 8 + j;
      pk.u[j] = (k < HW) ? ydup[oo][HW - k] : (u16)0;
    }
    xfr_sw[b * 3584 + ((kb * 8 + at) * 4 + quad) * 16 + m] = pk.v;
  }

  // xfe: 4 rows x 8 shifts x 60 uint4
  uint4* xfe4 = (uint4*)xfe;
  for (int idx = t; idx < 4 * 8 * 60; idx += 256) {
    const int oo = idx / 480;
    const int rem = idx - oo * 480;
    const int S = rem / 60;
    const int g = rem - S * 60;
    const int c = rg * 4 + oo;
    union { u16 u[8]; uint4 v; } pk;
#pragma unroll
    for (int j = 0; j < 8; ++j) pk.u[j] = ydup[oo][g * 8 + j + S];  // <= 487 < 588
    xfe4[((size_t)(b * NC + c) * 8 + S) * 60 + g] = pk.v;
  }
}

// ---- Stage 2: circular correlation via MFMA (exact R0 form) ----
__global__ __launch_bounds__(256, 2) void k_cooc(const uint4* __restrict__ xfr_sw,
                                                 const u16* __restrict__ xfe,
                                                 u32* __restrict__ W) {
  const int b     = blockIdx.x;
  const int cpair = blockIdx.y;
  const int t     = threadIdx.x;

  __shared__ __align__(16) uint4 Abuf[3584];   // 57344 B, frag order
  __shared__ __align__(16) u16 Obuf[32 * 200]; // 12800 B

  { // flat coalesced staging (xfr_sw is XCD-L2 resident)
    const uint4* src = xfr_sw + b * 3584;
    for (int j = t; j < 3584; j += 256) Abuf[j] = src[j];
  }
  __syncthreads();

  const int lane = t & 63;
  const int wv   = t >> 6;       // p-tiles {wv, wv+4, wv+8} (+12 for wave 0)
  const int n    = lane & 15;
  const int quad = lane >> 4;
  const u16* xbase = xfe + ((size_t)(b * NC) * 8) * CL + (n & 8) + quad * 8
                   + (size_t)(n & 7) * CL;

  for (int c2 = 0; c2 < 2; ++c2) {
    const int c = cpair * 2 + c2;
    const u16* xc = xbase + (size_t)c * (8 * CL);

    floatx4 acc[8][4];
#pragma unroll
    for (int at = 0; at < 8; ++at)
#pragma unroll
      for (int j = 0; j < 4; ++j) acc[at][j] = (floatx4){0.f, 0.f, 0.f, 0.f};

    for (int kb = 0; kb < 7; ++kb) {
      bf16x8 af[8];
#pragma unroll
      for (int at = 0; at < 8; ++at)   // lane-contiguous: base + lane*16B, no conflicts
        af[at] = *((const bf16x8*)&Abuf[(kb * 8 + at) * 64 + lane]);

#define DO_PT(JC)                                                                \
      {                                                                          \
        const int p0 = (wv + 4 * (JC)) * 16;                                     \
        const bf16x8 bv = *((const bf16x8*)&xc[p0 + kb * 32]);                   \
        _Pragma("unroll")                                                        \
        for (int at = 0; at < 8; ++at)                                           \
          acc[at][JC] = __builtin_amdgcn_mfma_f32_16x16x32_bf16(af[at], bv,      \
                                                                acc[at][JC], 0, 0, 0); \
      }
      DO_PT(0)
      DO_PT(1)
      DO_PT(2)
      if (wv == 0) { DO_PT(3) }
#undef DO_PT
    }

#define EPI(JC)                                                                  \
    {                                                                            \
      const int p = (wv + 4 * (JC)) * 16 + n;                                    \
      if (p < HW) {                                                              \
        _Pragma("unroll")                                                        \
        for (int a0t = 0; a0t < 2; ++a0t) {                                      \
          _Pragma("unroll")                                                      \
          for (int rr = 0; rr < 4; ++rr) {                                       \
            float v = fmaxf(fmaxf(acc[a0t][JC][rr], acc[a0t + 2][JC][rr]),       \
                            fmaxf(acc[a0t + 4][JC][rr], acc[a0t + 6][JC][rr]));  \
            const int a1 = a0t * 16 + quad * 4 + rr;                             \
            union { __hip_bfloat16 h; u16 u; } cv;                               \
            cv.h = __float2bfloat16(v);                                          \
            Obuf[a1 * 200 + p] = cv.u;                                           \
          }                                                                      \
        }                                                                        \
      }                                                                          \
    }
    EPI(0)
    EPI(1)
    EPI(2)
    if (wv == 0) { EPI(3) }
#undef EPI
    __syncthreads();

    { // coalesced store: 32 rows x 98 u32 into W[b][a1][c*98 + col]
      const u32* O32 = (const u32*)Obuf;
      u32* Wb = W + ((size_t)b * 32) * WROW + c * 98;
      for (int j = t; j < 32 * 98; j += 256) {
        const int row = (int)(((unsigned)j * 10700u) >> 20);   // j / 98
        const int col = j - row * 98;
        Wb[row * WROW + col] = O32[row * 100 + col];
      }
    }
    __syncthreads();
  }
}

__device__ __forceinline__ float blo(u32 v) { return __uint_as_float(v << 16); }
__device__ __forceinline__ float bhi(u32 v) { return __uint_as_float(v & 0xffff0000u); }

// ---- Stage 3: per-slot max, vectorized uint4 with a1 lane-split (exact R0 form) ----
__global__ __launch_bounds__(256) void k_max(const u32* __restrict__ W,
                                             float* __restrict__ out,
                                             float* __restrict__ parts) {
  const int t = threadIdx.x;
  const int wv = t >> 6, lane = t & 63;
  const int g = lane >> 4, ol = lane & 15;
  const int octet = blockIdx.x * 64 + wv * 16 + ol;   // 0..16383
  const int b  = octet >> 11;                          // 2048 octets / batch
  const int r0 = (octet & 2047) << 3;
  const uint4* Wb = (const uint4*)(W + (size_t)b * 32 * WROW);

  float m[8];
#pragma unroll
  for (int j = 0; j < 8; ++j) m[j] = 0.f;

#pragma unroll
  for (int k = 0; k < 8; ++k) {
    const int a1 = g * 8 + k;
    const int s = (r0 - ((a1 * 8704) & 16383)) & 16383;   // 8-aligned
    const uint4 v = Wb[(a1 * WROW + (s >> 1)) >> 2];
    m[0] = fmaxf(m[0], blo(v.x)); m[1] = fmaxf(m[1], bhi(v.x));
    m[2] = fmaxf(m[2], blo(v.y)); m[3] = fmaxf(m[3], bhi(v.y));
    m[4] = fmaxf(m[4], blo(v.z)); m[5] = fmaxf(m[5], bhi(v.z));
    m[6] = fmaxf(m[6], blo(v.w)); m[7] = fmaxf(m[7], bhi(v.w));
    if (s < 8704) {   // second contributor s+16384 < 25088
      const uint4 v2 = Wb[((a1 * WROW + (s >> 1)) >> 2) + 2048];
      m[0] = fmaxf(m[0], blo(v2.x)); m[1] = fmaxf(m[1], bhi(v2.x));
      m[2] = fmaxf(m[2], blo(v2.y)); m[3] = fmaxf(m[3], bhi(v2.y));
      m[4] = fmaxf(m[4], blo(v2.z)); m[5] = fmaxf(m[5], bhi(v2.z));
      m[6] = fmaxf(m[6], blo(v2.w)); m[7] = fmaxf(m[7], bhi(v2.w));
    }
  }

  // combine the 4 a1-groups (lanes stride 16)
#pragma unroll
  for (int j = 0; j < 8; ++j) {
    m[j] = fmaxf(m[j], __shfl_xor(m[j], 16, 64));
    m[j] = fmaxf(m[j], __shfl_xor(m[j], 32, 64));
  }

  float s2 = 0.f;
  if (g == 0) {
    float4 s0, s1;
    s0.x = sqrtf(m[0]); s0.y = sqrtf(m[1]); s0.z = sqrtf(m[2]); s0.w = sqrtf(m[3]);
    s1.x = sqrtf(m[4]); s1.y = sqrtf(m[5]); s1.z = sqrtf(m[6]); s1.w = sqrtf(m[7]);
    float4* op = (float4*)(out + (size_t)octet * 8);
    op[0] = s0; op[1] = s1;
    s2 = ((m[0] + m[1]) + (m[2] + m[3])) + ((m[4] + m[5]) + (m[6] + m[7]));
  }

  // per-batch sum of c_ij^2: wave reduce (non-g0 lanes carry 0) then block
#pragma unroll
  for (int off = 32; off > 0; off >>= 1) s2 += __shfl_down(s2, off, 64);
  __shared__ float part[4];
  if (lane == 0) part[wv] = s2;
  __syncthreads();
  if (t == 0)
    parts[blockIdx.x] = part[0] + part[1] + part[2] + part[3];
}

// ---- Stage 4 (R15): normalize, float4-vectorized (128 blocks, 1 float4/thread).
// Same i=0..31 scalar parts-sum order and same per-element divide as R0 ->
// bit-identical output; strictly less launch/issue work than the 512-block form. ----
__global__ __launch_bounds__(256) void k_norm(const float* __restrict__ parts,
                                              float* __restrict__ out) {
  const int b = blockIdx.x >> 4;    // 16 blocks per batch, wave-uniform
  const int gid = blockIdx.x * 256 + threadIdx.x;   // float4 index, 32768 total
  float s = 0.f;
#pragma unroll
  for (int i = 0; i < 32; ++i) s += parts[b * 32 + i];   // scalar loads, L1-hot
  const float den = s + 1e-11f;
  float4* o4 = (float4*)out;
  float4 v = o4[gid];
  v.x /= den; v.y /= den; v.z /= den; v.w /= den;
  o4[gid] = v;
}

extern "C" void kernel_launch(void* const* d_in, const int* in_sizes, int n_in,
                              void* d_out, int out_size, void* d_ws, size_t ws_size,
                              hipStream_t stream) {
  const float* x  = (const float*)d_in[0];   // (8,512,16,16) fp32
  const float* wc = (const float*)d_in[1];   // (128,512) fp32

  char* ws = (char*)d_ws;
  uint4* xfr_sw = (uint4*)(ws + OFF_XFRSW);
  u16*   xfe    = (u16*)(ws + OFF_XFE);
  u32*   W      = (u32*)(ws + OFF_W);
  float* Y      = (float*)(ws + OFF_Y);
  u16*   xbT    = (u16*)(ws + OFF_XBT);
  u16*   wb     = (u16*)(ws + OFF_WB);
  float* parts  = (float*)(ws + OFF_PARTS);

  k_cast<<<544, 256, 0, stream>>>(x, wc, xbT, wb);
  k_conv<<<dim3(NB, 16), 256, 0, stream>>>(xbT, wb, Y);
  k_blur<<<dim3(NB, 32), 256, 0, stream>>>(Y, xfr_sw, xfe);
  k_cooc<<<dim3(NB, 64), 256, 0, stream>>>(xfr_sw, xfe, W);
  k_max<<<256, 256, 0, stream>>>(W, (float*)d_out, parts);
  k_norm<<<(NB * 16384) / (256 * 4), 256, 0, stream>>>(parts, (float*)d_out);
}